// Round 1
// baseline (509.930 us; speedup 1.0000x reference)
//
#include <hip/hip_runtime.h>
#include <hip/hip_bf16.h>

// GraphSageLayer on MI355X.
// B=4, N=4096, D_IN=REP=D_OUT=128.
// Pipeline: proj (nodes->3 reps, bf16) -> agg (adj @ in_rep, adj^T @ out_rep) -> final (concat @ W_upd^T, tanh).
// All matmuls via v_mfma_f32_16x16x32_bf16; fp32 inputs converted to bf16 in flight (abs tol 1.98e-2 permits).

typedef __attribute__((ext_vector_type(8))) short short8;
typedef __attribute__((ext_vector_type(4))) float f32x4;
typedef __attribute__((ext_vector_type(4))) unsigned short u16x4;

#define MFMA(a, b, c) __builtin_amdgcn_mfma_f32_16x16x32_bf16(a, b, c, 0, 0, 0)

__device__ __forceinline__ unsigned short f2bf(float x) {
  union { float f; unsigned u; } v; v.f = x;
  unsigned r = v.u + 0x7FFFu + ((v.u >> 16) & 1u);   // RNE to bf16
  return (unsigned short)(r >> 16);
}

__device__ __forceinline__ short8 pack8(float4 a, float4 b) {
  short8 v;
  v[0] = (short)f2bf(a.x); v[1] = (short)f2bf(a.y); v[2] = (short)f2bf(a.z); v[3] = (short)f2bf(a.w);
  v[4] = (short)f2bf(b.x); v[5] = (short)f2bf(b.y); v[6] = (short)f2bf(b.z); v[7] = (short)f2bf(b.w);
  return v;
}

// ---------------------------------------------------------------------------
// Kernel 1: projections. rep = elu(nodes @ W^T + b) for W_in/W_out/W_node.
// grid = (128 m-tiles, 3 weights). No LDS: direct-global MFMA fragments.
// A-operand = nodes rows (m = node), B-operand = W rows (n = r feature).
// D layout: row(m=node) = quad*4+reg, col(n=r) = lane&15.
//   wsel 0/1 -> write rep_t[b][r][j] (4 consecutive j per lane -> 8B store)
//   wsel 2   -> write node_rep[b][j][r] (scalar 2B stores; only 4.2 MB)
// ---------------------------------------------------------------------------
__global__ __launch_bounds__(256) void proj_kernel(
    const float* __restrict__ nodes,   // [16384][128]
    const float* __restrict__ W_in, const float* __restrict__ b_in,
    const float* __restrict__ W_out, const float* __restrict__ b_out,
    const float* __restrict__ W_node, const float* __restrict__ b_node,
    unsigned short* __restrict__ in_rep_t,   // [4][128][4096]
    unsigned short* __restrict__ out_rep_t,  // [4][128][4096]
    unsigned short* __restrict__ node_rep)   // [4][4096][128]
{
  const int wsel = blockIdx.y;
  const float* W    = (wsel == 0) ? W_in  : (wsel == 1) ? W_out  : W_node;
  const float* bias = (wsel == 0) ? b_in  : (wsel == 1) ? b_out  : b_node;

  const int tid  = threadIdx.x;
  const int lane = tid & 63;
  const int w    = tid >> 6;
  const int q    = lane >> 4;
  const int r15  = lane & 15;
  const int m0   = blockIdx.x * 128 + w * 32;   // node base for this wave

  f32x4 acc[2][8];
#pragma unroll
  for (int mt = 0; mt < 2; ++mt)
#pragma unroll
    for (int nt = 0; nt < 8; ++nt) acc[mt][nt] = (f32x4)0.0f;

#pragma unroll
  for (int ks = 0; ks < 4; ++ks) {
    const int k0 = ks * 32 + q * 8;
    short8 a[2];
#pragma unroll
    for (int mt = 0; mt < 2; ++mt) {
      const float* p = nodes + (size_t)(m0 + mt * 16 + r15) * 128 + k0;
      a[mt] = pack8(*(const float4*)p, *(const float4*)(p + 4));
    }
#pragma unroll
    for (int nt = 0; nt < 8; ++nt) {
      const float* p = W + (size_t)(nt * 16 + r15) * 128 + k0;
      short8 bv = pack8(*(const float4*)p, *(const float4*)(p + 4));
      acc[0][nt] = MFMA(a[0], bv, acc[0][nt]);
      acc[1][nt] = MFMA(a[1], bv, acc[1][nt]);
    }
  }

#pragma unroll
  for (int nt = 0; nt < 8; ++nt) {
    const int rcol = nt * 16 + r15;
    const float bv = bias[rcol];
#pragma unroll
    for (int mt = 0; mt < 2; ++mt) {
      const int g0 = m0 + mt * 16 + q * 4;   // global node of reg 0
      float x[4];
#pragma unroll
      for (int c = 0; c < 4; ++c) {
        float t = acc[mt][nt][c] + bv;
        x[c] = (t > 0.f) ? t : (expf(t) - 1.f);   // ELU
      }
      if (wsel < 2) {
        unsigned short* rep = (wsel == 0) ? in_rep_t : out_rep_t;
        const int b = g0 >> 12, j = g0 & 4095;
        u16x4 o;
#pragma unroll
        for (int c = 0; c < 4; ++c) o[c] = f2bf(x[c]);
        *(u16x4*)&rep[((size_t)b << 19) + (size_t)rcol * 4096 + j] = o;
      } else {
#pragma unroll
        for (int c = 0; c < 4; ++c)
          node_rep[(size_t)(g0 + c) * 128 + rcol] = f2bf(x[c]);
      }
    }
  }
}

// ---------------------------------------------------------------------------
// Kernel 2: aggregations. One launch, 512 wgs:
//   blocks [0,256):   in_agg[i,v]  = sum_j adj[b][i][j] * in_rep[j][v]
//   blocks [256,512): out_agg[i,v] = sum_j adj[b][j][i] * out_rep[j][v]
// MFMA-A = rep_t[b][v][j] (bf16, direct-global frags, L2-hot).
// MFMA-B = adj tile [n=i][k=j] in LDS (fp32 read coalesced -> bf16, stride 40
// padding; transposed staging for the out_agg half). Double-buffered, one
// barrier per K-step. D: row(m=v)=quad*4+reg, col(n=i)=lane&15 ->
// agg[b][i][v0..v0+3] as one 8B store.
// ---------------------------------------------------------------------------
#define AGG_NT 64
#define LDS_STRIDE 40   // 32 + 8 pad: rows 16B-aligned, b128 reads 2-way (free)

template <bool TC>
__device__ __forceinline__ void agg_body(
    const float* __restrict__ adjb,        // adj + b*2^24
    const unsigned short* __restrict__ rep, // rep_t + b*2^19
    unsigned short* __restrict__ agg,       // agg + b*2^19
    unsigned short* lds,                    // [2][AGG_NT*LDS_STRIDE]
    int n0)
{
  const int tid  = threadIdx.x;
  const int lane = tid & 63;
  const int w    = tid >> 6;
  const int q    = lane >> 4;
  const int r15  = lane & 15;

  const unsigned short* arow[2];
#pragma unroll
  for (int mt = 0; mt < 2; ++mt)
    arow[mt] = rep + (size_t)(w * 32 + mt * 16 + r15) * 4096 + q * 8;

  // staging geometry (512 float4 slots = 2 per thread, contiguous pair)
  int st_i, st_j;                 // B: row i, col j4 base | C: col i4 base, row j
  const float* st_base;
  if (!TC) {                      // tile adj[n0+i][kk*32+j], i in [0,64), j in [0,32)
    st_i = tid >> 2;              // i  in [0,64)
    st_j = (tid & 3) * 8;         // j4 in {0,8,16,24}
    st_base = adjb + (size_t)(n0 + st_i) * 4096 + st_j;
  } else {                        // tile adj[kk*32+j][n0+i]
    st_j = tid >> 3;              // j  in [0,32)
    st_i = (tid & 7) * 8;         // i4 in {0,...,56}
    st_base = adjb + (size_t)st_j * 4096 + n0 + st_i;
  }

  f32x4 acc[2][4];
#pragma unroll
  for (int mt = 0; mt < 2; ++mt)
#pragma unroll
    for (int nt = 0; nt < 4; ++nt) acc[mt][nt] = (f32x4)0.0f;

  float4 pf0, pf1;
  short8 a_cur[2], a_nxt[2];

  // prologue: tile 0
  {
    const float* p = st_base;           // kk = 0
    pf0 = *(const float4*)p; pf1 = *(const float4*)(p + 4);
    a_cur[0] = *(const short8*)(arow[0]);
    a_cur[1] = *(const short8*)(arow[1]);
    if (!TC) {
      *(short8*)&lds[st_i * LDS_STRIDE + st_j] = pack8(pf0, pf1);
    } else {
      unsigned short* d = &lds[st_i * LDS_STRIDE + st_j];
      d[0 * LDS_STRIDE] = f2bf(pf0.x); d[1 * LDS_STRIDE] = f2bf(pf0.y);
      d[2 * LDS_STRIDE] = f2bf(pf0.z); d[3 * LDS_STRIDE] = f2bf(pf0.w);
      d[4 * LDS_STRIDE] = f2bf(pf1.x); d[5 * LDS_STRIDE] = f2bf(pf1.y);
      d[6 * LDS_STRIDE] = f2bf(pf1.z); d[7 * LDS_STRIDE] = f2bf(pf1.w);
    }
  }
  __syncthreads();

  for (int kk = 0; kk < 128; ++kk) {
    const int cur = kk & 1;
    unsigned short* ldsc = lds + cur * (AGG_NT * LDS_STRIDE);
    unsigned short* ldsn = lds + (cur ^ 1) * (AGG_NT * LDS_STRIDE);

    if (kk < 127) {   // prefetch next tile (global) + next A frags
      const float* p = TC ? (st_base + (size_t)(kk + 1) * 32 * 4096)
                          : (st_base + (kk + 1) * 32);
      pf0 = *(const float4*)p; pf1 = *(const float4*)(p + 4);
      a_nxt[0] = *(const short8*)(arow[0] + (kk + 1) * 32);
      a_nxt[1] = *(const short8*)(arow[1] + (kk + 1) * 32);
    }

#pragma unroll
    for (int nt = 0; nt < 4; ++nt) {
      short8 bv = *(const short8*)&ldsc[(nt * 16 + r15) * LDS_STRIDE + q * 8];
      acc[0][nt] = MFMA(a_cur[0], bv, acc[0][nt]);
      acc[1][nt] = MFMA(a_cur[1], bv, acc[1][nt]);
    }

    if (kk < 127) {
      if (!TC) {
        *(short8*)&ldsn[st_i * LDS_STRIDE + st_j] = pack8(pf0, pf1);
      } else {
        unsigned short* d = &ldsn[st_i * LDS_STRIDE + st_j];
        d[0 * LDS_STRIDE] = f2bf(pf0.x); d[1 * LDS_STRIDE] = f2bf(pf0.y);
        d[2 * LDS_STRIDE] = f2bf(pf0.z); d[3 * LDS_STRIDE] = f2bf(pf0.w);
        d[4 * LDS_STRIDE] = f2bf(pf1.x); d[5 * LDS_STRIDE] = f2bf(pf1.y);
        d[6 * LDS_STRIDE] = f2bf(pf1.z); d[7 * LDS_STRIDE] = f2bf(pf1.w);
      }
      a_cur[0] = a_nxt[0]; a_cur[1] = a_nxt[1];
    }
    __syncthreads();
  }

  // epilogue: agg[b][i][v], 4 consecutive v per lane -> 8B store
#pragma unroll
  for (int mt = 0; mt < 2; ++mt) {
    const int v0 = w * 32 + mt * 16 + q * 4;
#pragma unroll
    for (int nt = 0; nt < 4; ++nt) {
      const int i = n0 + nt * 16 + r15;
      u16x4 o;
#pragma unroll
      for (int c = 0; c < 4; ++c) o[c] = f2bf(acc[mt][nt][c]);
      *(u16x4*)&agg[(size_t)i * 128 + v0] = o;
    }
  }
}

__global__ __launch_bounds__(256, 2) void agg_kernel(
    const float* __restrict__ adj,
    const unsigned short* __restrict__ in_rep_t,
    const unsigned short* __restrict__ out_rep_t,
    unsigned short* __restrict__ in_agg,
    unsigned short* __restrict__ out_agg)
{
  __shared__ unsigned short lds[2 * AGG_NT * LDS_STRIDE];
  const int id = blockIdx.x;
  const bool tc = (id >= 256);
  const int t  = id & 255;
  const int b  = t >> 6;
  const int n0 = (t & 63) * AGG_NT;
  const float* adjb = adj + ((size_t)b << 24);
  if (tc)
    agg_body<true>(adjb, out_rep_t + ((size_t)b << 19), out_agg + ((size_t)b << 19), lds, n0);
  else
    agg_body<false>(adjb, in_rep_t + ((size_t)b << 19), in_agg + ((size_t)b << 19), lds, n0);
}

// ---------------------------------------------------------------------------
// Kernel 3: out[n,o] = tanh(sum_k upd[n,k] * W_upd[o,k] + b_upd[o]),
// upd = concat(in_agg, node_rep, out_agg) along k. No LDS.
// MFMA-A = W_upd rows (m=o, fp32->bf16), MFMA-B = upd rows (n=node, bf16).
// D: row(m=o)=quad*4+reg -> 4 consecutive o per lane -> float4 store.
// ---------------------------------------------------------------------------
__global__ __launch_bounds__(256) void final_kernel(
    const unsigned short* __restrict__ in_agg,    // [16384][128]
    const unsigned short* __restrict__ node_rep,  // [16384][128]
    const unsigned short* __restrict__ out_agg,   // [16384][128]
    const float* __restrict__ W_upd,              // [128][384]
    const float* __restrict__ b_upd,              // [128]
    float* __restrict__ out)                      // [16384][128]
{
  const int tid  = threadIdx.x;
  const int lane = tid & 63;
  const int w    = tid >> 6;
  const int q    = lane >> 4;
  const int r15  = lane & 15;
  const int n0   = blockIdx.x * 64;

  const unsigned short* srcs[3] = { in_agg, node_rep, out_agg };

  f32x4 acc[2][4];
#pragma unroll
  for (int mt = 0; mt < 2; ++mt)
#pragma unroll
    for (int nt = 0; nt < 4; ++nt) acc[mt][nt] = (f32x4)0.0f;

  for (int ks = 0; ks < 12; ++ks) {
    const unsigned short* src = srcs[ks >> 2];
    const int col0 = (ks & 3) * 32 + q * 8;
    short8 a[2];
#pragma unroll
    for (int mt = 0; mt < 2; ++mt) {
      const float* p = W_upd + (size_t)(w * 32 + mt * 16 + r15) * 384 + ks * 32 + q * 8;
      a[mt] = pack8(*(const float4*)p, *(const float4*)(p + 4));
    }
#pragma unroll
    for (int nt = 0; nt < 4; ++nt) {
      const int g = n0 + nt * 16 + r15;
      short8 bv = *(const short8*)&src[(size_t)g * 128 + col0];
      acc[0][nt] = MFMA(a[0], bv, acc[0][nt]);
      acc[1][nt] = MFMA(a[1], bv, acc[1][nt]);
    }
  }

#pragma unroll
  for (int mt = 0; mt < 2; ++mt) {
    const int o0 = w * 32 + mt * 16 + q * 4;
#pragma unroll
    for (int nt = 0; nt < 4; ++nt) {
      const int g = n0 + nt * 16 + r15;
      f32x4 ov;
#pragma unroll
      for (int c = 0; c < 4; ++c) ov[c] = tanhf(acc[mt][nt][c] + b_upd[o0 + c]);
      *(f32x4*)&out[(size_t)g * 128 + o0] = ov;
    }
  }
}

// ---------------------------------------------------------------------------
extern "C" void kernel_launch(void* const* d_in, const int* in_sizes, int n_in,
                              void* d_out, int out_size, void* d_ws, size_t ws_size,
                              hipStream_t stream) {
  (void)in_sizes; (void)n_in; (void)out_size; (void)ws_size;
  const float* nodes  = (const float*)d_in[0];
  const float* adj    = (const float*)d_in[1];
  const float* W_in   = (const float*)d_in[2];
  const float* b_in   = (const float*)d_in[3];
  const float* W_out  = (const float*)d_in[4];
  const float* b_out  = (const float*)d_in[5];
  const float* W_node = (const float*)d_in[6];
  const float* b_node = (const float*)d_in[7];
  const float* W_upd  = (const float*)d_in[8];
  const float* b_upd  = (const float*)d_in[9];
  float* out = (float*)d_out;

  // workspace: 5 bf16 arrays of 4*128*4096 = 2,097,152 elements each (20 MB)
  unsigned short* ws = (unsigned short*)d_ws;
  const size_t SZ = (size_t)4 * 128 * 4096;
  unsigned short* in_rep_t  = ws;
  unsigned short* out_rep_t = ws + SZ;
  unsigned short* node_rep  = ws + 2 * SZ;
  unsigned short* in_agg    = ws + 3 * SZ;
  unsigned short* out_agg   = ws + 4 * SZ;

  proj_kernel<<<dim3(128, 3), 256, 0, stream>>>(
      nodes, W_in, b_in, W_out, b_out, W_node, b_node,
      in_rep_t, out_rep_t, node_rep);
  agg_kernel<<<512, 256, 0, stream>>>(adj, in_rep_t, out_rep_t, in_agg, out_agg);
  final_kernel<<<256, 256, 0, stream>>>(in_agg, node_rep, out_agg, W_upd, b_upd, out);
}

// Round 2
// 505.213 us; speedup vs baseline: 1.0093x; 1.0093x over previous
//
#include <hip/hip_runtime.h>
#include <hip/hip_bf16.h>

// GraphSageLayer on MI355X. B=4, N=4096, D_IN=REP=D_OUT=128.
// proj (nodes->3 reps, bf16) -> agg (adj @ in_rep, adj^T @ out_rep) -> final (concat @ W_upd^T, tanh).
// All matmuls via v_mfma_f32_16x16x32_bf16; fp32 converted to bf16 in flight.
//
// R2 changes (latency-bound fix: HBM 24%, occ 20%, MfmaUtil 7% in R1):
//  - agg: BK=128 epochs (32 barriers instead of 128), full-epoch prefetch of
//    adj tile + next A-fragments (~8KB in flight/wave), LDS stride 136 shorts
//    (rotation-4 banks: conflict-free b128, 16B-aligned rows), TC staging via
//    paired-row ds_write_b32 (was 8-way-conflicted ds_write_b16).
//  - proj: m-tile 64 -> grid 768; final: n-tile 32 -> grid 512; K fully
//    unrolled so global loads batch ahead of MFMA.

typedef __attribute__((ext_vector_type(8))) short short8;
typedef __attribute__((ext_vector_type(4))) float f32x4;
typedef __attribute__((ext_vector_type(4))) unsigned short u16x4;

#define MFMA(a, b, c) __builtin_amdgcn_mfma_f32_16x16x32_bf16(a, b, c, 0, 0, 0)

__device__ __forceinline__ unsigned short f2bf(float x) {
  union { float f; unsigned u; } v; v.f = x;
  unsigned r = v.u + 0x7FFFu + ((v.u >> 16) & 1u);   // RNE to bf16
  return (unsigned short)(r >> 16);
}

__device__ __forceinline__ short8 pack8(float4 a, float4 b) {
  short8 v;
  v[0] = (short)f2bf(a.x); v[1] = (short)f2bf(a.y); v[2] = (short)f2bf(a.z); v[3] = (short)f2bf(a.w);
  v[4] = (short)f2bf(b.x); v[5] = (short)f2bf(b.y); v[6] = (short)f2bf(b.z); v[7] = (short)f2bf(b.w);
  return v;
}

// ---------------------------------------------------------------------------
// Kernel 1: projections. rep = elu(nodes @ W^T + b). grid=(256 m-tiles, 3).
// Per wave: m=16 nodes, n=128 r. All A-frags loaded up front, K unrolled.
// ---------------------------------------------------------------------------
__global__ __launch_bounds__(256) void proj_kernel(
    const float* __restrict__ nodes,   // [16384][128]
    const float* __restrict__ W_in, const float* __restrict__ b_in,
    const float* __restrict__ W_out, const float* __restrict__ b_out,
    const float* __restrict__ W_node, const float* __restrict__ b_node,
    unsigned short* __restrict__ in_rep_t,   // [4][128][4096]
    unsigned short* __restrict__ out_rep_t,  // [4][128][4096]
    unsigned short* __restrict__ node_rep)   // [4][4096][128]
{
  const int wsel = blockIdx.y;
  const float* W    = (wsel == 0) ? W_in  : (wsel == 1) ? W_out  : W_node;
  const float* bias = (wsel == 0) ? b_in  : (wsel == 1) ? b_out  : b_node;

  const int tid  = threadIdx.x;
  const int lane = tid & 63;
  const int w    = tid >> 6;
  const int q    = lane >> 4;
  const int r15  = lane & 15;
  const int m0   = blockIdx.x * 64 + w * 16;   // node base for this wave

  f32x4 acc[8];
#pragma unroll
  for (int nt = 0; nt < 8; ++nt) acc[nt] = (f32x4)0.0f;

  short8 a[4];
#pragma unroll
  for (int ks = 0; ks < 4; ++ks) {
    const float* p = nodes + (size_t)(m0 + r15) * 128 + ks * 32 + q * 8;
    a[ks] = pack8(*(const float4*)p, *(const float4*)(p + 4));
  }

#pragma unroll
  for (int ks = 0; ks < 4; ++ks)
#pragma unroll
    for (int nt = 0; nt < 8; ++nt) {
      const float* p = W + (size_t)(nt * 16 + r15) * 128 + ks * 32 + q * 8;
      short8 bv = pack8(*(const float4*)p, *(const float4*)(p + 4));
      acc[nt] = MFMA(a[ks], bv, acc[nt]);
    }

#pragma unroll
  for (int nt = 0; nt < 8; ++nt) {
    const int rcol = nt * 16 + r15;
    const float bv = bias[rcol];
    const int g0 = m0 + q * 4;   // global node of reg 0
    float x[4];
#pragma unroll
    for (int c = 0; c < 4; ++c) {
      float t = acc[nt][c] + bv;
      x[c] = (t > 0.f) ? t : (expf(t) - 1.f);   // ELU
    }
    if (wsel < 2) {
      unsigned short* rep = (wsel == 0) ? in_rep_t : out_rep_t;
      const int b = g0 >> 12, j = g0 & 4095;
      u16x4 o;
#pragma unroll
      for (int c = 0; c < 4; ++c) o[c] = f2bf(x[c]);
      *(u16x4*)&rep[((size_t)b << 19) + (size_t)rcol * 4096 + j] = o;
    } else {
#pragma unroll
      for (int c = 0; c < 4; ++c)
        node_rep[(size_t)(g0 + c) * 128 + rcol] = f2bf(x[c]);
    }
  }
}

// ---------------------------------------------------------------------------
// Kernel 2: aggregations. 512 wgs:
//   blocks [0,256):   in_agg[i,v]  = sum_j adj[b][i][j] * in_rep[j][v]
//   blocks [256,512): out_agg[i,v] = sum_j adj[b][j][i] * out_rep[j][v]
// BK=128 epochs (32 total), double-buffered LDS [i=64][k=128] bf16 with row
// stride 136 shorts (68 dwords, rotation 4 -> conflict-free b128 reads+writes,
// 16B-aligned rows). Prefetch next adj tile + next A-frags one full epoch
// ahead. MFMA-A = rep_t[b][v][j] (direct global, L2-hot); MFMA-B = LDS tile.
// D: row(m=v)=quad*4+reg, col(n=i)=lane&15 -> agg[b][i][v0..3] 8B store.
// ---------------------------------------------------------------------------
#define AGG_BK 128
#define AGG_ST 136   // shorts per LDS row: 128 + 8 pad
#define AGG_BUF (64 * AGG_ST)

template <bool TC>
__device__ __forceinline__ void agg_body(
    const float* __restrict__ adjb,         // adj + b*2^24
    const unsigned short* __restrict__ rep, // rep_t + b*2^19
    unsigned short* __restrict__ agg,       // agg + b*2^19
    unsigned short* lds,                    // [2][AGG_BUF]
    int n0)
{
  const int tid  = threadIdx.x;
  const int lane = tid & 63;
  const int w    = tid >> 6;
  const int q    = lane >> 4;
  const int r15  = lane & 15;

  const unsigned short* arow[2];
#pragma unroll
  for (int mt = 0; mt < 2; ++mt)
    arow[mt] = rep + (size_t)(w * 32 + mt * 16 + r15) * 4096 + q * 8;

  // staging geometry
  int sti, stko, j0 = 0;
  const float* ld0; const float* ld1 = nullptr;
  if (!TC) {              // tile adj[n0+i][e*128+k]: thread = row sti, 32 cols
    sti  = tid >> 2;                 // i in [0,64)
    stko = (tid & 3) * 32;           // k base {0,32,64,96}
    ld0  = adjb + (size_t)(n0 + sti) * 4096 + stko;
  } else {                // tile adj[e*128+j][n0+i]: thread = rows j0,j0+1 x 16 cols
    j0   = (tid >> 2) * 2;           // j in {0,2,...,126}
    sti  = (tid & 3) * 16;           // i base {0,16,32,48}
    ld0  = adjb + (size_t)j0 * 4096 + n0 + sti;
    ld1  = ld0 + 4096;
  }

  f32x4 acc[2][4];
#pragma unroll
  for (int mt = 0; mt < 2; ++mt)
#pragma unroll
    for (int nt = 0; nt < 4; ++nt) acc[mt][nt] = (f32x4)0.0f;

  float4 pf[8];
  short8 a_cur[8], a_nxt[8];

  auto stage_load = [&](int e) {
    if (!TC) {
      const float* p = ld0 + e * AGG_BK;
#pragma unroll
      for (int s = 0; s < 8; ++s) pf[s] = ((const float4*)p)[s];
    } else {
      const float* p0 = ld0 + (size_t)e * AGG_BK * 4096;
      const float* p1 = ld1 + (size_t)e * AGG_BK * 4096;
#pragma unroll
      for (int s = 0; s < 4; ++s) { pf[s] = ((const float4*)p0)[s]; pf[4 + s] = ((const float4*)p1)[s]; }
    }
  };
  auto stage_write = [&](unsigned short* dst) {
    if (!TC) {
#pragma unroll
      for (int s = 0; s < 4; ++s)
        *(short8*)&dst[sti * AGG_ST + stko + s * 8] = pack8(pf[2 * s], pf[2 * s + 1]);
    } else {
      const float* r0 = (const float*)&pf[0];   // row j0, 16 floats
      const float* r1 = (const float*)&pf[4];   // row j0+1
#pragma unroll
      for (int c = 0; c < 16; ++c) {
        unsigned v = (unsigned)f2bf(r0[c]) | ((unsigned)f2bf(r1[c]) << 16);
        *(unsigned*)&dst[(sti + c) * AGG_ST + j0] = v;  // element (i, j0/j0+1)
      }
    }
  };
  auto load_a = [&](int e, short8* d) {
#pragma unroll
    for (int sub = 0; sub < 4; ++sub)
#pragma unroll
      for (int mt = 0; mt < 2; ++mt)
        d[sub * 2 + mt] = *(const short8*)(arow[mt] + e * AGG_BK + sub * 32);
  };

  stage_load(0);
  load_a(0, a_cur);
  stage_write(lds);
  __syncthreads();

  for (int e = 0; e < 32; ++e) {
    unsigned short* cur = lds + (e & 1) * AGG_BUF;
    unsigned short* nxt = lds + ((e & 1) ^ 1) * AGG_BUF;

    if (e < 31) { stage_load(e + 1); load_a(e + 1, a_nxt); }

#pragma unroll
    for (int sub = 0; sub < 4; ++sub)
#pragma unroll
      for (int nt = 0; nt < 4; ++nt) {
        short8 bv = *(const short8*)&cur[(nt * 16 + r15) * AGG_ST + sub * 32 + q * 8];
        acc[0][nt] = MFMA(a_cur[sub * 2 + 0], bv, acc[0][nt]);
        acc[1][nt] = MFMA(a_cur[sub * 2 + 1], bv, acc[1][nt]);
      }

    if (e < 31) {
      stage_write(nxt);
#pragma unroll
      for (int i = 0; i < 8; ++i) a_cur[i] = a_nxt[i];
    }
    __syncthreads();
  }

  // epilogue: agg[b][i][v], 4 consecutive v per lane -> 8B store
#pragma unroll
  for (int mt = 0; mt < 2; ++mt) {
    const int v0 = w * 32 + mt * 16 + q * 4;
#pragma unroll
    for (int nt = 0; nt < 4; ++nt) {
      const int i = n0 + nt * 16 + r15;
      u16x4 o;
#pragma unroll
      for (int c = 0; c < 4; ++c) o[c] = f2bf(acc[mt][nt][c]);
      *(u16x4*)&agg[(size_t)i * 128 + v0] = o;
    }
  }
}

__global__ __launch_bounds__(256, 2) void agg_kernel(
    const float* __restrict__ adj,
    const unsigned short* __restrict__ in_rep_t,
    const unsigned short* __restrict__ out_rep_t,
    unsigned short* __restrict__ in_agg,
    unsigned short* __restrict__ out_agg)
{
  __shared__ unsigned short lds[2 * AGG_BUF];
  const int id = blockIdx.x;
  const bool tc = (id >= 256);
  const int t  = id & 255;
  const int b  = t >> 6;
  const int n0 = (t & 63) * 64;
  const float* adjb = adj + ((size_t)b << 24);
  if (tc)
    agg_body<true>(adjb, out_rep_t + ((size_t)b << 19), out_agg + ((size_t)b << 19), lds, n0);
  else
    agg_body<false>(adjb, in_rep_t + ((size_t)b << 19), in_agg + ((size_t)b << 19), lds, n0);
}

// ---------------------------------------------------------------------------
// Kernel 3: out[n,o] = tanh(sum_k upd[n,k] * W_upd[o,k] + b_upd[o]),
// upd = concat(in_agg, node_rep, out_agg). grid=512 (n-tile 32). K fully
// unrolled. MFMA-A = W_upd rows (m=o), MFMA-B = upd rows (n=node).
// D: row(m=o)=quad*4+reg -> float4 store.
// ---------------------------------------------------------------------------
__global__ __launch_bounds__(256) void final_kernel(
    const unsigned short* __restrict__ in_agg,    // [16384][128]
    const unsigned short* __restrict__ node_rep,  // [16384][128]
    const unsigned short* __restrict__ out_agg,   // [16384][128]
    const float* __restrict__ W_upd,              // [128][384]
    const float* __restrict__ b_upd,              // [128]
    float* __restrict__ out)                      // [16384][128]
{
  const int tid  = threadIdx.x;
  const int lane = tid & 63;
  const int w    = tid >> 6;
  const int q    = lane >> 4;
  const int r15  = lane & 15;
  const int n0   = blockIdx.x * 32;

  const unsigned short* srcs[3] = { in_agg, node_rep, out_agg };

  f32x4 acc[2][2];
#pragma unroll
  for (int mt = 0; mt < 2; ++mt)
#pragma unroll
    for (int nt = 0; nt < 2; ++nt) acc[mt][nt] = (f32x4)0.0f;

#pragma unroll
  for (int ks = 0; ks < 12; ++ks) {
    const unsigned short* src = srcs[ks >> 2];
    const int col0 = (ks & 3) * 32 + q * 8;
    short8 a[2];
#pragma unroll
    for (int mt = 0; mt < 2; ++mt) {
      const float* p = W_upd + (size_t)(w * 32 + mt * 16 + r15) * 384 + ks * 32 + q * 8;
      a[mt] = pack8(*(const float4*)p, *(const float4*)(p + 4));
    }
#pragma unroll
    for (int nt = 0; nt < 2; ++nt) {
      const int g = n0 + nt * 16 + r15;
      short8 bv = *(const short8*)&src[(size_t)g * 128 + col0];
      acc[0][nt] = MFMA(a[0], bv, acc[0][nt]);
      acc[1][nt] = MFMA(a[1], bv, acc[1][nt]);
    }
  }

#pragma unroll
  for (int mt = 0; mt < 2; ++mt) {
    const int o0 = w * 32 + mt * 16 + q * 4;
#pragma unroll
    for (int nt = 0; nt < 2; ++nt) {
      const int g = n0 + nt * 16 + r15;
      f32x4 ov;
#pragma unroll
      for (int c = 0; c < 4; ++c) ov[c] = tanhf(acc[mt][nt][c] + b_upd[o0 + c]);
      *(f32x4*)&out[(size_t)g * 128 + o0] = ov;
    }
  }
}

// ---------------------------------------------------------------------------
extern "C" void kernel_launch(void* const* d_in, const int* in_sizes, int n_in,
                              void* d_out, int out_size, void* d_ws, size_t ws_size,
                              hipStream_t stream) {
  (void)in_sizes; (void)n_in; (void)out_size; (void)ws_size;
  const float* nodes  = (const float*)d_in[0];
  const float* adj    = (const float*)d_in[1];
  const float* W_in   = (const float*)d_in[2];
  const float* b_in   = (const float*)d_in[3];
  const float* W_out  = (const float*)d_in[4];
  const float* b_out  = (const float*)d_in[5];
  const float* W_node = (const float*)d_in[6];
  const float* b_node = (const float*)d_in[7];
  const float* W_upd  = (const float*)d_in[8];
  const float* b_upd  = (const float*)d_in[9];
  float* out = (float*)d_out;

  unsigned short* ws = (unsigned short*)d_ws;
  const size_t SZ = (size_t)4 * 128 * 4096;
  unsigned short* in_rep_t  = ws;
  unsigned short* out_rep_t = ws + SZ;
  unsigned short* node_rep  = ws + 2 * SZ;
  unsigned short* in_agg    = ws + 3 * SZ;
  unsigned short* out_agg   = ws + 4 * SZ;

  proj_kernel<<<dim3(256, 3), 256, 0, stream>>>(
      nodes, W_in, b_in, W_out, b_out, W_node, b_node,
      in_rep_t, out_rep_t, node_rep);
  agg_kernel<<<512, 256, 0, stream>>>(adj, in_rep_t, out_rep_t, in_agg, out_agg);
  final_kernel<<<512, 256, 0, stream>>>(in_agg, node_rep, out_agg, W_upd, b_upd, out);
}